// Round 7
// baseline (2869.598 us; speedup 1.0000x reference)
//
#include <hip/hip_runtime.h>

#define Bsz 2048
#define Ssz 96
#define Fsz 32
#define Hsz 256
#define Osz 6
#define LAsz 32
#define RT 8                  // batch rows per block; grid = 256 = 1 block/CU
#define NSTEP (Ssz + LAsz)
#define NTHR 512              // 8 waves
#define NKT 9                 // K-tiles of 32 over virtual K = 32(x) + 256(h) = 288
#define NGT 64                // gate tiles of 16 (4*256/16)
#define XHW 296               // ushort row stride of xh_* (592 B, 16-aligned)
#define GLW 1044              // f32 row stride of gate_lds
#define RECB 48               // bytes per (gt,kt,lane) weight record: 8*(w0,w1,w2)

typedef __attribute__((ext_vector_type(8))) short  short8;   // 8 bf16 MFMA A/B frag
typedef __attribute__((ext_vector_type(4))) float  f32x4;    // MFMA C/D frag
typedef __attribute__((ext_vector_type(4))) unsigned int uint4v;

__device__ __forceinline__ short8 as_s8(uint4v v) {
    union { uint4v u; short8 s; } c; c.u = v; return c.s;
}
#define MFMAB(A, B, C) __builtin_amdgcn_mfma_f32_16x16x32_bf16(as_s8(A), (B), (C), 0, 0, 0)

__device__ __forceinline__ unsigned short bf16_rne(float f) {
    unsigned int u = __float_as_uint(f);
    return (unsigned short)((u + 0x7FFFu + ((u >> 16) & 1u)) >> 16);
}
__device__ __forceinline__ float bf16_to_f(unsigned short h) {
    return __uint_as_float((unsigned int)h << 16);
}

// ---------- accurate f64 exp (|rel err| ~1e-14) ----------
__device__ __forceinline__ double exp_d(double x) {
    x = fmin(fmax(x, -700.0), 700.0);
    const double LOG2E = 1.4426950408889634074;
    const double LN2HI = 6.93147180369123816490e-01;
    const double LN2LO = 1.90821492927058770002e-10;
    double n = __builtin_rint(x * LOG2E);
    double r = fma(-n, LN2HI, x);
    r = fma(-n, LN2LO, r);
    double p = 2.5052108385441718775e-08;
    p = fma(p, r, 2.7557319223985890653e-07);
    p = fma(p, r, 2.7557319223985892511e-06);
    p = fma(p, r, 2.4801587301587301566e-05);
    p = fma(p, r, 1.9841269841269841253e-04);
    p = fma(p, r, 1.3888888888888889419e-03);
    p = fma(p, r, 8.3333333333333332177e-03);
    p = fma(p, r, 4.1666666666666664354e-02);
    p = fma(p, r, 1.6666666666666665741e-01);
    p = fma(p, r, 5.0e-01);
    p = fma(p, r, 1.0);
    p = fma(p, r, 1.0);
    long long bits = (long long)(1023 + (int)n) << 52;
    return p * __longlong_as_double(bits);
}
__device__ __forceinline__ double recip_d(double y) {
    double r = (double)(1.0f / (float)y);
    r = fma(fma(-y, r, 1.0), r, r);
    r = fma(fma(-y, r, 1.0), r, r);
    r = fma(fma(-y, r, 1.0), r, r);
    return r;
}
__device__ __forceinline__ double sigmoid_d(double x) { return recip_d(1.0 + exp_d(-x)); }
__device__ __forceinline__ double tanh_d(double x) {
    double ax = fabs(x);
    double t = exp_d(-2.0 * ax);
    double r = (1.0 - t) * recip_d(1.0 + t);
    return x >= 0.0 ? r : -r;
}

// ---------- pre-pass: pack W into TRIPLE-split bf16 MFMA A-fragments ----------
// record idx = (gt*NKT + kt)*64 + lane, 48 B: [8 w0][8 w1][8 w2] (ushort bf16).
// lane supplies A[gate = gt*16 + (lane&15)][vk = kt*32 + (lane>>4)*8 + i].
// vk<32 -> W_ih[gate][vk]; else W_hh[gate][vk-32]. B side uses the SAME vk
// convention, so any internal k-permutation of the MFMA cancels.
__global__ void pack_w(const float* __restrict__ W_ih,
                       const float* __restrict__ W_hh,
                       unsigned short* __restrict__ wfrag)
{
    int idx = blockIdx.x * 256 + threadIdx.x;
    if (idx >= NGT * NKT * 64) return;
    int L  = idx & 63;
    int tk = idx >> 6;
    int kt = tk % NKT, gt = tk / NKT;
    int gate = gt * 16 + (L & 15);
    int kg   = L >> 4;
    unsigned short* p = wfrag + (size_t)idx * (RECB / 2);
    #pragma unroll
    for (int i = 0; i < 8; ++i) {
        int vk = kt * 32 + kg * 8 + i;
        float wv = (vk < Fsz) ? W_ih[(size_t)gate * Fsz + vk]
                              : W_hh[(size_t)gate * Hsz + (vk - Fsz)];
        unsigned short w0 = bf16_rne(wv);
        float r1 = wv - bf16_to_f(w0);              // exact (cancellation)
        unsigned short w1 = bf16_rne(r1);
        float r2 = r1 - bf16_to_f(w1);              // exact
        unsigned short w2 = bf16_rne(r2);
        p[i]      = w0;
        p[8 + i]  = w1;
        p[16 + i] = w2;
    }
}

// one gate-tile pair: 9 K-tiles, prefetch dbuf, 3 magnitude-grouped acc chains
// per gt: c0 = w0h0; c1 = w0h1 + w1h0; c2 = w0h2 + w1h1 + w2h0.
// All register indices are compile-time (named vars, macro-literal G0/G1).
#define PAIR(G0, G1)                                                         \
  {                                                                          \
    const char* wp0 = wb + (size_t)(G0) * (NKT * 64 * RECB);                 \
    const char* wp1 = wb + (size_t)(G1) * (NKT * 64 * RECB);                 \
    uint4v a00c = *(const uint4v*)(wp0);                                     \
    uint4v a01c = *(const uint4v*)(wp0 + 16);                                \
    uint4v a02c = *(const uint4v*)(wp0 + 32);                                \
    uint4v a10c = *(const uint4v*)(wp1);                                     \
    uint4v a11c = *(const uint4v*)(wp1 + 16);                                \
    uint4v a12c = *(const uint4v*)(wp1 + 32);                                \
    short8 b0c = *(const short8*)&xh_hi[boff];                               \
    short8 b1c = *(const short8*)&xh_mid[boff];                              \
    short8 b2c = *(const short8*)&xh_lo[boff];                               \
    f32x4 c00 = {0.f,0.f,0.f,0.f}, c01 = {0.f,0.f,0.f,0.f};                  \
    f32x4 c02 = {0.f,0.f,0.f,0.f}, c10 = {0.f,0.f,0.f,0.f};                  \
    f32x4 c11 = {0.f,0.f,0.f,0.f}, c12 = {0.f,0.f,0.f,0.f};                  \
    _Pragma("unroll 1")                                                      \
    for (int kt = 0; kt < NKT; ++kt) {                                       \
      int kn = (kt < NKT - 1) ? (kt + 1) : 0;                                \
      const char* n0 = wp0 + kn * (64 * RECB);                               \
      const char* n1 = wp1 + kn * (64 * RECB);                               \
      uint4v a00n = *(const uint4v*)(n0);                                    \
      uint4v a01n = *(const uint4v*)(n0 + 16);                               \
      uint4v a02n = *(const uint4v*)(n0 + 32);                               \
      uint4v a10n = *(const uint4v*)(n1);                                    \
      uint4v a11n = *(const uint4v*)(n1 + 16);                               \
      uint4v a12n = *(const uint4v*)(n1 + 32);                               \
      short8 b0n = *(const short8*)&xh_hi[boff + kn * 32];                   \
      short8 b1n = *(const short8*)&xh_mid[boff + kn * 32];                  \
      short8 b2n = *(const short8*)&xh_lo[boff + kn * 32];                   \
      c02 = MFMAB(a00c, b2c, c02);                                           \
      c12 = MFMAB(a10c, b2c, c12);                                           \
      c00 = MFMAB(a00c, b0c, c00);                                           \
      c10 = MFMAB(a10c, b0c, c10);                                           \
      c01 = MFMAB(a00c, b1c, c01);                                           \
      c11 = MFMAB(a10c, b1c, c11);                                           \
      c02 = MFMAB(a01c, b1c, c02);                                           \
      c12 = MFMAB(a11c, b1c, c12);                                           \
      c01 = MFMAB(a01c, b0c, c01);                                           \
      c11 = MFMAB(a11c, b0c, c11);                                           \
      c02 = MFMAB(a02c, b0c, c02);                                           \
      c12 = MFMAB(a12c, b0c, c12);                                           \
      a00c = a00n; a01c = a01n; a02c = a02n;                                 \
      a10c = a10n; a11c = a11n; a12c = a12n;                                 \
      b0c = b0n; b1c = b1n; b2c = b2n;                                       \
    }                                                                        \
    if (r16 < RT) {                                                          \
      f32x4 s0 = (c02 + c01) + c00;                                          \
      f32x4 s1 = (c12 + c11) + c10;                                          \
      *(f32x4*)&gate_lds[r16 * GLW + ((w * 8 + (G0)) * 16) + kg * 4] = s0;   \
      *(f32x4*)&gate_lds[r16 * GLW + ((w * 8 + (G1)) * 16) + kg * 4] = s1;   \
    }                                                                        \
  }

__global__ __launch_bounds__(NTHR, 2) void lstm_persist(
    const float* __restrict__ x,
    const unsigned short* __restrict__ wfrag,
    const float* __restrict__ b_ih, const float* __restrict__ b_hh,
    const float* __restrict__ W_fc, const float* __restrict__ b_fc,
    float* __restrict__ out)
{
    // xh (triple-split bf16): 16 rows (8 valid, 8 zero), cols vk 0-31 = x, 32-287 = h
    __shared__ __align__(16) unsigned short xh_hi [16 * XHW];   // 9.25 KB
    __shared__ __align__(16) unsigned short xh_mid[16 * XHW];   // 9.25 KB
    __shared__ __align__(16) unsigned short xh_lo [16 * XHW];   // 9.25 KB
    __shared__ __align__(16) float gate_lds[RT * GLW];          // 33.4 KB
    __shared__ __align__(16) float h_f32[RT * Hsz];             // 8 KB (STE readout)
    __shared__ float  wfc_lds[Osz * Hsz];                       // 6 KB
    __shared__ double o_lds[RT][Osz];

    const int tid   = threadIdx.x;
    const int row0  = blockIdx.x * RT;
    const int w     = tid >> 6;                    // wave id
    const int l     = tid & 63;
    const int j     = (w << 5) + (l & 31);         // activation channel owned
    const int q     = l >> 5;
    const int rbase = q * 4;                       // activation rows owned
    const int r16   = l & 15;                      // MFMA: batch row (N)
    const int kg    = l >> 4;                      // MFMA: k-group

    for (int i = tid; i < 16 * XHW; i += NTHR) { xh_hi[i] = 0; xh_mid[i] = 0; xh_lo[i] = 0; }
    for (int i = tid; i < Osz * Hsz; i += NTHR) wfc_lds[i] = W_fc[i];

    const double bias0 = (double)b_ih[0 * Hsz + j] + (double)b_hh[0 * Hsz + j];
    const double bias1 = (double)b_ih[1 * Hsz + j] + (double)b_hh[1 * Hsz + j];
    const double bias2 = (double)b_ih[2 * Hsz + j] + (double)b_hh[2 * Hsz + j];
    const double bias3 = (double)b_ih[3 * Hsz + j] + (double)b_hh[3 * Hsz + j];

    double c_reg[4];
    #pragma unroll
    for (int r = 0; r < 4; ++r) c_reg[r] = 0.0;

    // wave w owns gate-tiles w*8 .. w*8+7
    const char* wb  = (const char*)wfrag + ((size_t)(w * 8) * NKT * 64 + l) * RECB;
    const int  boff = r16 * XHW + kg * 8;

    __syncthreads();

    for (int t = 0; t < NSTEP; ++t) {
        // ---- stage x[:, t] (or o feedback) triple-split into xh cols 0-31 ----
        if (tid < RT * Fsz) {
            int r = tid >> 5, f = tid & 31;
            int ts = (t < Ssz) ? t : (t - Ssz);
            float v;
            if (t >= Ssz && f < Osz) v = (float)o_lds[r][f];
            else v = x[((size_t)(row0 + r) * Ssz + ts) * Fsz + f];
            unsigned short v0 = bf16_rne(v);
            float r1 = v - bf16_to_f(v0);
            unsigned short v1 = bf16_rne(r1);
            float r2 = r1 - bf16_to_f(v1);
            xh_hi [r * XHW + f] = v0;
            xh_mid[r * XHW + f] = v1;
            xh_lo [r * XHW + f] = bf16_rne(r2);
        }
        __syncthreads();                                 // A: xh complete (x + h)

        // ---- gate GEMM on the matrix pipe: triple-split bf16, 3 chains/gt ----
        PAIR(0, 1)
        PAIR(2, 3)
        PAIR(4, 5)
        PAIR(6, 7)
        __syncthreads();                                 // B: gates published

        // ---- activations: EXACT f64 path of rounds 0/2/4/5 ----
        float gv0[4], gv1[4], gv2[4], gv3[4];
        #pragma unroll
        for (int rr = 0; rr < 4; ++rr) {
            int rowb = (rbase + rr) * GLW;
            gv0[rr] = gate_lds[rowb + 0 * Hsz + j];
            gv1[rr] = gate_lds[rowb + 1 * Hsz + j];
            gv2[rr] = gate_lds[rowb + 2 * Hsz + j];
            gv3[rr] = gate_lds[rowb + 3 * Hsz + j];
        }
        #pragma unroll
        for (int rr = 0; rr < 4; ++rr) {
            double t0 = bias0 + (double)gv0[rr];
            double t1 = bias1 + (double)gv1[rr];
            double t2 = bias2 + (double)gv2[rr];
            double t3 = bias3 + (double)gv3[rr];
            double si = sigmoid_d(t0);
            double sf = sigmoid_d(t1);
            double tg = tanh_d(t2);
            double so = sigmoid_d(t3);
            double cn = fma(sf, c_reg[rr], si * tg);
            c_reg[rr] = cn;
            float hf = (float)(so * tanh_d(cn));
            int row = rbase + rr;
            unsigned short h0 = bf16_rne(hf);
            float r1 = hf - bf16_to_f(h0);
            unsigned short h1 = bf16_rne(r1);
            float r2 = r1 - bf16_to_f(h1);
            xh_hi [row * XHW + Fsz + j] = h0;
            xh_mid[row * XHW + Fsz + j] = h1;
            xh_lo [row * XHW + Fsz + j] = bf16_rne(r2);
            if (t >= Ssz - 1) h_f32[row * Hsz + j] = hf;   // exact h for STE readout
        }

        // ---- readout: wave w owns row w (STE in f32, dot in f64 — unchanged) ----
        if (t >= Ssz - 1) {
            __syncthreads();                              // C: h complete
            double a0 = 0.0, a1 = 0.0, a2 = 0.0, a3 = 0.0, a4 = 0.0, a5 = 0.0;
            #pragma unroll
            for (int m = 0; m < 4; ++m) {
                int k = l + 64 * m;
                float hv = h_f32[w * Hsz + k];
                bool b = hv > 0.0f;
                a0 += b ? (double)wfc_lds[0 * Hsz + k] : 0.0;
                a1 += b ? (double)wfc_lds[1 * Hsz + k] : 0.0;
                a2 += b ? (double)wfc_lds[2 * Hsz + k] : 0.0;
                a3 += b ? (double)wfc_lds[3 * Hsz + k] : 0.0;
                a4 += b ? (double)wfc_lds[4 * Hsz + k] : 0.0;
                a5 += b ? (double)wfc_lds[5 * Hsz + k] : 0.0;
            }
            #pragma unroll
            for (int off = 32; off >= 1; off >>= 1) {
                a0 += __shfl_down(a0, off, 64);
                a1 += __shfl_down(a1, off, 64);
                a2 += __shfl_down(a2, off, 64);
                a3 += __shfl_down(a3, off, 64);
                a4 += __shfl_down(a4, off, 64);
                a5 += __shfl_down(a5, off, 64);
            }
            if (l == 0) {
                size_t base = ((size_t)(row0 + w) * (LAsz + 1) + (t - (Ssz - 1))) * Osz;
                double o;
                o = (double)b_fc[0] + a0; o_lds[w][0] = o; out[base + 0] = (float)o;
                o = (double)b_fc[1] + a1; o_lds[w][1] = o; out[base + 1] = (float)o;
                o = (double)b_fc[2] + a2; o_lds[w][2] = o; out[base + 2] = (float)o;
                o = (double)b_fc[3] + a3; o_lds[w][3] = o; out[base + 3] = (float)o;
                o = (double)b_fc[4] + a4; o_lds[w][4] = o; out[base + 4] = (float)o;
                o = (double)b_fc[5] + a5; o_lds[w][5] = o; out[base + 5] = (float)o;
            }
            __syncthreads();                              // D: o_lds published
        }
        // next iteration's barrier A orders this step's h/x writes vs MFMA reads
    }
}

extern "C" void kernel_launch(void* const* d_in, const int* in_sizes, int n_in,
                              void* d_out, int out_size, void* d_ws, size_t ws_size,
                              hipStream_t stream)
{
    const float* x    = (const float*)d_in[0];
    const float* W_ih = (const float*)d_in[1];
    const float* W_hh = (const float*)d_in[2];
    const float* b_ih = (const float*)d_in[3];
    const float* b_hh = (const float*)d_in[4];
    const float* W_fc = (const float*)d_in[5];
    const float* b_fc = (const float*)d_in[6];
    float* out = (float*)d_out;

    unsigned short* wfrag = (unsigned short*)d_ws;   // 64*9*64*48 B = 1.69 MB

    pack_w<<<dim3((NGT * NKT * 64 + 255) / 256), dim3(256), 0, stream>>>(
        W_ih, W_hh, wfrag);

    lstm_persist<<<dim3(Bsz / RT), dim3(NTHR), 0, stream>>>(
        x, wfrag, b_ih, b_hh, W_fc, b_fc, out);
}

// Round 8
// 1892.993 us; speedup vs baseline: 1.5159x; 1.5159x over previous
//
#include <hip/hip_runtime.h>

#define Bsz 2048
#define Ssz 96
#define Fsz 32
#define Hsz 256
#define Osz 6
#define LAsz 32
#define RT 8                  // batch rows per block; grid = 256 = 1 block/CU
#define NSTEP (Ssz + LAsz)
#define NTHR 512              // 8 waves
#define NKT 9                 // K-tiles of 32 over virtual K = 32(x) + 256(h) = 288
#define NGT 64                // gate tiles of 16 (4*256/16)
#define GLW 1044              // f32 row stride of gate_lds
// fp16 2-way split scaling (all exact powers of 2):
//   w' = w*2^10, h' = h*2^10; w0=f16(w'), w1=f16((w'-w0)*2^11); same for h.
//   gate = (c0 + c1*2^-11 + c2*2^-22) * 2^-20,  c0=w0h0, c1=w0h1+w1h0, c2=w1h1.
#define SCL   1024.0f
#define SRES  2048.0f
#define INV_SR   4.8828125e-4f          // 2^-11
#define INV_SR2  2.384185791015625e-7f  // 2^-22
#define INV_SWH  9.5367431640625e-07    // 2^-20 (applied in f64 combine)

typedef __attribute__((ext_vector_type(8))) short    short8;
typedef __attribute__((ext_vector_type(8))) _Float16 half8;
typedef __attribute__((ext_vector_type(4))) float    f32x4;
typedef __attribute__((ext_vector_type(4))) unsigned int uint4v;

__device__ __forceinline__ half8 as_h8(uint4v v) {
    union { uint4v u; half8 h; } c; c.u = v; return c.h;
}
__device__ __forceinline__ half8 as_h8s(short8 v) {
    union { short8 s; half8 h; } c; c.s = v; return c.h;
}
#define MFMAF16(A, B, C) \
    __builtin_amdgcn_mfma_f32_16x16x32_f16(as_h8(A), as_h8s(B), (C), 0, 0, 0)

__device__ __forceinline__ unsigned short f16_rne(float f) {
    union { _Float16 h; unsigned short u; } c; c.h = (_Float16)f; return c.u;
}
__device__ __forceinline__ float f16_to_f(unsigned short u) {
    union { _Float16 h; unsigned short u; } c; c.u = u; return (float)c.h;
}

// fragment LDS index: [kt][half][slot][elem] ushorts; slot for (r16,kg) = (kg<<4)|r16 = lane
#define FIDX(kt, half, slot, elem) (((((kt) * 2 + (half)) * 64) + (slot)) * 8 + (elem))

// ---------- accurate f64 exp (|rel err| ~1e-14) ----------
__device__ __forceinline__ double exp_d(double x) {
    x = fmin(fmax(x, -700.0), 700.0);
    const double LOG2E = 1.4426950408889634074;
    const double LN2HI = 6.93147180369123816490e-01;
    const double LN2LO = 1.90821492927058770002e-10;
    double n = __builtin_rint(x * LOG2E);
    double r = fma(-n, LN2HI, x);
    r = fma(-n, LN2LO, r);
    double p = 2.5052108385441718775e-08;
    p = fma(p, r, 2.7557319223985890653e-07);
    p = fma(p, r, 2.7557319223985892511e-06);
    p = fma(p, r, 2.4801587301587301566e-05);
    p = fma(p, r, 1.9841269841269841253e-04);
    p = fma(p, r, 1.3888888888888889419e-03);
    p = fma(p, r, 8.3333333333333332177e-03);
    p = fma(p, r, 4.1666666666666664354e-02);
    p = fma(p, r, 1.6666666666666665741e-01);
    p = fma(p, r, 5.0e-01);
    p = fma(p, r, 1.0);
    p = fma(p, r, 1.0);
    long long bits = (long long)(1023 + (int)n) << 52;
    return p * __longlong_as_double(bits);
}
__device__ __forceinline__ double recip_d(double y) {
    double r = (double)(1.0f / (float)y);
    r = fma(fma(-y, r, 1.0), r, r);
    r = fma(fma(-y, r, 1.0), r, r);
    r = fma(fma(-y, r, 1.0), r, r);
    return r;
}
__device__ __forceinline__ double sigmoid_d(double x) { return recip_d(1.0 + exp_d(-x)); }
__device__ __forceinline__ double tanh_d(double x) {
    double ax = fabs(x);
    double t = exp_d(-2.0 * ax);
    double r = (1.0 - t) * recip_d(1.0 + t);
    return x >= 0.0 ? r : -r;
}

// ---------- pre-pass: pack W into scaled fp16 2-way-split MFMA A-fragments ----------
// record idx = (gt*NKT + kt)*64 + lane, 32 B: [8 f16 w0][8 f16 w1].
// lane supplies A[gate = gt*16 + (lane&15)][vk = kt*32 + (lane>>4)*8 + i].
// vk<32 -> W_ih, else W_hh (same vk convention on B side -> k-permutation cancels).
__global__ void pack_w(const float* __restrict__ W_ih,
                       const float* __restrict__ W_hh,
                       unsigned short* __restrict__ wfrag)
{
    int idx = blockIdx.x * 256 + threadIdx.x;
    if (idx >= NGT * NKT * 64) return;
    int L  = idx & 63;
    int tk = idx >> 6;
    int kt = tk % NKT, gt = tk / NKT;
    int gate = gt * 16 + (L & 15);
    int kg   = L >> 4;
    unsigned short* p = wfrag + (size_t)idx * 16;
    #pragma unroll
    for (int i = 0; i < 8; ++i) {
        int vk = kt * 32 + kg * 8 + i;
        float wv = (vk < Fsz) ? W_ih[(size_t)gate * Fsz + vk]
                              : W_hh[(size_t)gate * Hsz + (vk - Fsz)];
        float ws = wv * SCL;
        unsigned short w0 = f16_rne(ws);
        float r1 = ws - f16_to_f(w0);            // exact (Sterbenz)
        p[i]     = w0;
        p[8 + i] = f16_rne(r1 * SRES);
    }
}

__global__ __launch_bounds__(NTHR, 2) void lstm_persist(
    const float* __restrict__ x,
    const unsigned short* __restrict__ wfrag,
    const float* __restrict__ b_ih, const float* __restrict__ b_hh,
    const float* __restrict__ W_fc, const float* __restrict__ b_fc,
    float* __restrict__ out)
{
    // per-lane-slot fragment tiles: read addr = base + lane*16 (conflict-benign)
    __shared__ __align__(16) unsigned short xfrag[NKT * 2 * 64 * 8];  // 18 KB
    __shared__ __align__(16) float gate_lds[RT * GLW];                // 33.4 KB
    __shared__ __align__(16) float h_f32[RT * Hsz];                   // 8 KB
    __shared__ float  wfc_lds[Osz * Hsz];                             // 6 KB
    __shared__ double o_lds[RT][Osz];

    const int tid   = threadIdx.x;
    const int row0  = blockIdx.x * RT;
    const int w     = tid >> 6;                    // wave id
    const int l     = tid & 63;
    const int j     = (w << 5) + (l & 31);         // activation channel owned
    const int q     = l >> 5;
    const int rbase = q * 4;                       // activation rows owned
    const int r16   = l & 15;                      // MFMA: batch row (N)
    const int kg    = l >> 4;                      // MFMA: k-group

    for (int i = tid; i < NKT * 2 * 64 * 8; i += NTHR) xfrag[i] = 0;
    for (int i = tid; i < Osz * Hsz; i += NTHR) wfc_lds[i] = W_fc[i];

    const double bias0 = (double)b_ih[0 * Hsz + j] + (double)b_hh[0 * Hsz + j];
    const double bias1 = (double)b_ih[1 * Hsz + j] + (double)b_hh[1 * Hsz + j];
    const double bias2 = (double)b_ih[2 * Hsz + j] + (double)b_hh[2 * Hsz + j];
    const double bias3 = (double)b_ih[3 * Hsz + j] + (double)b_hh[3 * Hsz + j];

    double c_reg[4];
    #pragma unroll
    for (int r = 0; r < 4; ++r) c_reg[r] = 0.0;

    // wave w owns gate-tiles w*8 .. w*8+7; lane's record base (ushort units)
    const unsigned short* wbase = wfrag + ((size_t)(w * 8) * NKT * 64 + l) * 16;
    const int ktw = w + 1;                         // h-write K-tile for this wave

    __syncthreads();

    for (int t = 0; t < NSTEP; ++t) {
        // ---- stage x[:, t] (or o feedback), scaled fp16 2-split, into kt=0 tile ----
        if (tid < RT * Fsz) {
            int r = tid >> 5, f = tid & 31;
            int ts = (t < Ssz) ? t : (t - Ssz);
            float v;
            if (t >= Ssz && f < Osz) v = (float)o_lds[r][f];
            else v = x[((size_t)(row0 + r) * Ssz + ts) * Fsz + f];
            float vs = v * SCL;
            unsigned short u0 = f16_rne(vs);
            float r1 = vs - f16_to_f(u0);
            int slot = ((f >> 3) << 4) | r;
            xfrag[FIDX(0, 0, slot, f & 7)] = u0;
            xfrag[FIDX(0, 1, slot, f & 7)] = f16_rne(r1 * SRES);
        }
        __syncthreads();                                 // A: fragments complete

        // ---- B-fragments to registers ONCE (18 x ds_read_b128, slot = lane) ----
        short8 bh[NKT], bl[NKT];
        #pragma unroll
        for (int kt = 0; kt < NKT; ++kt) {
            bh[kt] = *(const short8*)&xfrag[FIDX(kt, 0, l, 0)];
            bl[kt] = *(const short8*)&xfrag[FIDX(kt, 1, l, 0)];
        }

        // ---- gate GEMM: per gate-tile, 3 scale-matched chains, 4 MFMA/kt ----
        #pragma unroll 1
        for (int gt = 0; gt < 8; ++gt) {
            const unsigned short* wp = wbase + (size_t)gt * (NKT * 64 * 16);
            f32x4 c0 = {0.f, 0.f, 0.f, 0.f};
            f32x4 c1 = {0.f, 0.f, 0.f, 0.f};
            f32x4 c2 = {0.f, 0.f, 0.f, 0.f};
            #pragma unroll
            for (int kt = 0; kt < NKT; ++kt) {
                const uint4v* rec = (const uint4v*)(wp + (size_t)kt * 1024);
                uint4v a0 = rec[0];                      // w0 frag
                uint4v a1 = rec[1];                      // w1 frag
                c0 = MFMAF16(a0, bh[kt], c0);
                c1 = MFMAF16(a0, bl[kt], c1);
                c1 = MFMAF16(a1, bh[kt], c1);
                c2 = MFMAF16(a1, bl[kt], c2);
            }
            if (r16 < RT) {
                f32x4 s;
                s.x = fmaf(c2.x, INV_SR2, fmaf(c1.x, INV_SR, c0.x));
                s.y = fmaf(c2.y, INV_SR2, fmaf(c1.y, INV_SR, c0.y));
                s.z = fmaf(c2.z, INV_SR2, fmaf(c1.z, INV_SR, c0.z));
                s.w = fmaf(c2.w, INV_SR2, fmaf(c1.w, INV_SR, c0.w));
                // D: col(lane&15)=batch row, row(kg*4+reg)=gate-in-tile
                *(f32x4*)&gate_lds[r16 * GLW + ((w * 8 + gt) << 4) + (kg << 2)] = s;
            }
        }
        __syncthreads();                                 // B: gates published

        // ---- activations: EXACT f64 path (descale by 2^-20, exact) ----
        float gv0[4], gv1[4], gv2[4], gv3[4];
        #pragma unroll
        for (int rr = 0; rr < 4; ++rr) {
            int rowb = (rbase + rr) * GLW;
            gv0[rr] = gate_lds[rowb + 0 * Hsz + j];
            gv1[rr] = gate_lds[rowb + 1 * Hsz + j];
            gv2[rr] = gate_lds[rowb + 2 * Hsz + j];
            gv3[rr] = gate_lds[rowb + 3 * Hsz + j];
        }
        #pragma unroll
        for (int rr = 0; rr < 4; ++rr) {
            double t0 = bias0 + (double)gv0[rr] * INV_SWH;
            double t1 = bias1 + (double)gv1[rr] * INV_SWH;
            double t2 = bias2 + (double)gv2[rr] * INV_SWH;
            double t3 = bias3 + (double)gv3[rr] * INV_SWH;
            double si = sigmoid_d(t0);
            double sf = sigmoid_d(t1);
            double tg = tanh_d(t2);
            double so = sigmoid_d(t3);
            double cn = fma(sf, c_reg[rr], si * tg);
            c_reg[rr] = cn;
            float hf = (float)(so * tanh_d(cn));
            // h -> scaled fp16 2-split fragments (wave-uniform kt = w+1)
            int row = rbase + rr;
            int i32 = j & 31;
            int slot = ((i32 >> 3) << 4) | row;
            float hs = hf * SCL;
            unsigned short u0 = f16_rne(hs);
            float r1 = hs - f16_to_f(u0);
            xfrag[FIDX(ktw, 0, slot, i32 & 7)] = u0;
            xfrag[FIDX(ktw, 1, slot, i32 & 7)] = f16_rne(r1 * SRES);
            if (t >= Ssz - 1) h_f32[row * Hsz + j] = hf;   // exact h for STE readout
        }

        // ---- readout: wave w owns row w (STE in f32, dot in f64 — unchanged) ----
        if (t >= Ssz - 1) {
            __syncthreads();                              // C: h complete
            double a0 = 0.0, a1 = 0.0, a2 = 0.0, a3 = 0.0, a4 = 0.0, a5 = 0.0;
            #pragma unroll
            for (int m = 0; m < 4; ++m) {
                int k = l + 64 * m;
                float hv = h_f32[w * Hsz + k];
                bool b = hv > 0.0f;
                a0 += b ? (double)wfc_lds[0 * Hsz + k] : 0.0;
                a1 += b ? (double)wfc_lds[1 * Hsz + k] : 0.0;
                a2 += b ? (double)wfc_lds[2 * Hsz + k] : 0.0;
                a3 += b ? (double)wfc_lds[3 * Hsz + k] : 0.0;
                a4 += b ? (double)wfc_lds[4 * Hsz + k] : 0.0;
                a5 += b ? (double)wfc_lds[5 * Hsz + k] : 0.0;
            }
            #pragma unroll
            for (int off = 32; off >= 1; off >>= 1) {
                a0 += __shfl_down(a0, off, 64);
                a1 += __shfl_down(a1, off, 64);
                a2 += __shfl_down(a2, off, 64);
                a3 += __shfl_down(a3, off, 64);
                a4 += __shfl_down(a4, off, 64);
                a5 += __shfl_down(a5, off, 64);
            }
            if (l == 0) {
                size_t base = ((size_t)(row0 + w) * (LAsz + 1) + (t - (Ssz - 1))) * Osz;
                double o;
                o = (double)b_fc[0] + a0; o_lds[w][0] = o; out[base + 0] = (float)o;
                o = (double)b_fc[1] + a1; o_lds[w][1] = o; out[base + 1] = (float)o;
                o = (double)b_fc[2] + a2; o_lds[w][2] = o; out[base + 2] = (float)o;
                o = (double)b_fc[3] + a3; o_lds[w][3] = o; out[base + 3] = (float)o;
                o = (double)b_fc[4] + a4; o_lds[w][4] = o; out[base + 4] = (float)o;
                o = (double)b_fc[5] + a5; o_lds[w][5] = o; out[base + 5] = (float)o;
            }
            __syncthreads();                              // D: o_lds published
        }
        // next iteration's barrier A orders this step's h/x writes vs reads
    }
}

extern "C" void kernel_launch(void* const* d_in, const int* in_sizes, int n_in,
                              void* d_out, int out_size, void* d_ws, size_t ws_size,
                              hipStream_t stream)
{
    const float* x    = (const float*)d_in[0];
    const float* W_ih = (const float*)d_in[1];
    const float* W_hh = (const float*)d_in[2];
    const float* b_ih = (const float*)d_in[3];
    const float* b_hh = (const float*)d_in[4];
    const float* W_fc = (const float*)d_in[5];
    const float* b_fc = (const float*)d_in[6];
    float* out = (float*)d_out;

    unsigned short* wfrag = (unsigned short*)d_ws;   // 64*9*64*32 B = 1.125 MB

    pack_w<<<dim3((NGT * NKT * 64 + 255) / 256), dim3(256), 0, stream>>>(
        W_ih, W_hh, wfrag);

    lstm_persist<<<dim3(Bsz / RT), dim3(NTHR), 0, stream>>>(
        x, wfrag, b_ih, b_hh, W_fc, b_fc, out);
}